// Round 1
// baseline (244.212 us; speedup 1.0000x reference)
//
#include <hip/hip_runtime.h>

// Problem constants (match reference)
constexpr int Bn = 2;
constexpr int Ln = 1024;
constexpr int Dn = 768;
constexpr int Kn = 64;
constexpr int Hn = 128;          // MLP_HIDDEN
constexpr int KM1 = Kn - 1;      // 63 context positions
constexpr int Wn = Ln - Kn + 1;  // 961 windows
constexpr int WB = 8;            // windows per block (kernel B), rows per block (kernel A)
constexpr int WCHUNKS = (Wn + WB - 1) / WB;  // 121
constexpr float EPSf = 1e-8f;

// ---------------------------------------------------------------------------
// Kernel A: xw1[b,t,h] = x[b,t,:] @ w1[0:D, h]   for all 2048 rows
//           pew1[k,h]  = pos_emb[k,:] @ w1[D:2D, h] + b1[h]  for k < 63
//           also copies the unmodified head rows (t < 63) of x into out.
// 128 threads (one per h), 8 rows per block, row data staged in LDS.
// ---------------------------------------------------------------------------
__global__ __launch_bounds__(128)
void k_gemm1(const float* __restrict__ x, const float* __restrict__ pos_emb,
             const float* __restrict__ w1, const float* __restrict__ b1,
             float* __restrict__ xw1, float* __restrict__ pew1,
             float* __restrict__ out)
{
    __shared__ float xs[WB * Dn];  // 24 KiB
    const int tid = threadIdx.x;
    const int blk = blockIdx.x;

    if (blk < (Bn * Ln) / WB) {              // 256 blocks: x rows
        const int r0 = blk * WB;             // flat row index b*1024 + t
        for (int idx = tid; idx < WB * Dn; idx += 128)
            xs[idx] = x[r0 * Dn + idx];
        __syncthreads();

        // copy unmodified head rows (t < K-1) straight to output
        #pragma unroll
        for (int i = 0; i < WB; ++i) {
            const int r = r0 + i;
            if ((r & (Ln - 1)) < KM1) {
                for (int c = tid; c < Dn; c += 128)
                    out[r * Dn + c] = xs[i * Dn + c];
            }
        }

        const int h = tid;
        float acc[WB];
        #pragma unroll
        for (int i = 0; i < WB; ++i) acc[i] = 0.f;
        for (int c = 0; c < Dn; ++c) {
            const float wv = w1[c * Hn + h];   // coalesced across threads
            #pragma unroll
            for (int i = 0; i < WB; ++i)
                acc[i] = fmaf(xs[i * Dn + c], wv, acc[i]);  // LDS broadcast
        }
        #pragma unroll
        for (int i = 0; i < WB; ++i)
            xw1[(r0 + i) * Hn + h] = acc[i];
    } else {                                  // 8 blocks: pos_emb rows (63 total)
        const int k0 = (blk - (Bn * Ln) / WB) * WB;
        const int nv = min(WB, KM1 - k0);     // valid rows in this block
        for (int idx = tid; idx < nv * Dn; idx += 128)
            xs[idx] = pos_emb[k0 * Dn + idx];
        __syncthreads();

        const int h = tid;
        const float bias = b1[h];
        float acc[WB];
        #pragma unroll
        for (int i = 0; i < WB; ++i) acc[i] = bias;
        for (int c = 0; c < Dn; ++c) {
            const float wv = w1[(Dn + c) * Hn + h];
            #pragma unroll
            for (int i = 0; i < WB; ++i)
                acc[i] = fmaf(xs[i * Dn + c], wv, acc[i]);  // garbage for i>=nv, unused
        }
        for (int i = 0; i < nv; ++i)
            pew1[(k0 + i) * Hn + h] = acc[i];
    }
}

// ---------------------------------------------------------------------------
// Kernel B: per (b, chunk of 8 windows):
//   hbar[w,h] = mean_k relu(xw1[b,w0+w+k,h] + pew1[k,h])       (sliding window)
//   pred[w,d] = hbar[w,:] @ w2[:,d] + b2[d]
//   md        = x[b,w0+w+63,d] - pred ; update = -alpha*md
//   out row   = x + update ; accumulate sq / norm / cos partials -> atomics
// 256 threads. xw1 chunk (<=70 rows) staged in LDS.
// ---------------------------------------------------------------------------
__global__ __launch_bounds__(256)
void k_main(const float* __restrict__ x, const float* __restrict__ alpha_p,
            const float* __restrict__ w2, const float* __restrict__ b2,
            const float* __restrict__ xw1, const float* __restrict__ pew1,
            float* __restrict__ out, float* __restrict__ accum)
{
    __shared__ float xs[(WB + KM1 - 1) * Hn];  // 70*128 floats = 35 KiB
    __shared__ float part[2 * WB * Hn];        // 8 KiB
    __shared__ float hbar[WB * Hn];            // 4 KiB
    __shared__ float4 red[256];                // 4 KiB

    const int tid = threadIdx.x;
    const int b = blockIdx.x / WCHUNKS;
    const int chunk = blockIdx.x % WCHUNKS;
    const int w0 = chunk * WB;
    const int wcount = min(WB, Wn - w0);
    const int nrows = wcount + KM1 - 1;        // rows of xw1 needed
    const float alpha = alpha_p[0];

    // stage xw1 rows [w0, w0+nrows) of batch b
    const int rowbase = (b * Ln + w0) * Hn;
    for (int idx = tid; idx < nrows * Hn; idx += 256)
        xs[idx] = xw1[rowbase + idx];
    __syncthreads();

    // ---- step 1: sliding-window relu mean -> hbar -------------------------
    {
        const int h = tid & (Hn - 1);
        const int half = tid >> 7;             // 0: k=0..31, 1: k=32..62
        float s[WB];
        #pragma unroll
        for (int w = 0; w < WB; ++w) s[w] = 0.f;
        const int k0 = half * 32;
        const int k1 = half ? KM1 : 32;
        for (int k = k0; k < k1; ++k) {
            const float pv = pew1[k * Hn + h];
            #pragma unroll
            for (int w = 0; w < WB; ++w) {
                const float v = xs[(w + k) * Hn + h] + pv;  // in-bounds of array always
                s[w] += fmaxf(v, 0.f);
            }
        }
        #pragma unroll
        for (int w = 0; w < WB; ++w)
            part[(half * WB + w) * Hn + h] = s[w];
    }
    __syncthreads();
    for (int idx = tid; idx < WB * Hn; idx += 256)
        hbar[idx] = (part[idx] + part[WB * Hn + idx]) * (1.0f / 63.0f);
    __syncthreads();

    // ---- step 2: GEMM2 + delta/update/out + partials ----------------------
    float psq[WB], paa[WB], pab[WB], pbb[WB];
    #pragma unroll
    for (int w = 0; w < WB; ++w) { psq[w] = paa[w] = pab[w] = pbb[w] = 0.f; }

    for (int j = 0; j < 3; ++j) {              // 768 = 3 * 256
        const int d = tid + j * 256;
        const float bias = b2[d];
        float acc[WB];
        #pragma unroll
        for (int w = 0; w < WB; ++w) acc[w] = bias;
        for (int h = 0; h < Hn; ++h) {
            const float wv = w2[h * Dn + d];   // coalesced
            #pragma unroll
            for (int w = 0; w < WB; ++w)
                acc[w] = fmaf(hbar[w * Hn + h], wv, acc[w]);  // LDS broadcast
        }
        for (int w = 0; w < wcount; ++w) {
            const int row = b * Ln + w0 + w + KM1;
            const float cur = x[row * Dn + d];
            const float md = cur - acc[w];
            const float upd = -alpha * md;
            const float nb = cur + upd;
            out[row * Dn + d] = nb;
            psq[w] = fmaf(md, md, psq[w]);
            paa[w] = fmaf(cur, cur, paa[w]);
            pab[w] = fmaf(cur, nb, pab[w]);
            pbb[w] = fmaf(nb, nb, pbb[w]);
        }
    }

    // ---- per-window block reduction + atomics -----------------------------
    for (int w = 0; w < wcount; ++w) {
        red[tid] = make_float4(psq[w], paa[w], pab[w], pbb[w]);
        __syncthreads();
        if (tid < 128) {
            float4 m = red[tid], o = red[tid + 128];
            m.x += o.x; m.y += o.y; m.z += o.z; m.w += o.w;
            red[tid] = m;
        }
        __syncthreads();
        if (tid < 64) {
            float4 m = red[tid], o = red[tid + 64];
            float sx = m.x + o.x, sy = m.y + o.y, sz = m.z + o.z, sw = m.w + o.w;
            #pragma unroll
            for (int off = 32; off > 0; off >>= 1) {
                sx += __shfl_down(sx, off);
                sy += __shfl_down(sy, off);
                sz += __shfl_down(sz, off);
                sw += __shfl_down(sw, off);
            }
            if (tid == 0) {
                atomicAdd(&accum[0], sx);                       // sum of ||md||^2
                atomicAdd(&accum[1], alpha * sqrtf(sx));        // sum of ||update||
                const float na = fmaxf(sqrtf(sy), EPSf);
                const float nbn = fmaxf(sqrtf(sw), EPSf);
                atomicAdd(&accum[2], sz / (na * nbn));          // sum of cos
            }
        }
        __syncthreads();
    }
}

// ---------------------------------------------------------------------------
// Kernel C: finalize the 4 scalar outputs.
// ---------------------------------------------------------------------------
__global__ void k_final(const float* __restrict__ accum,
                        const float* __restrict__ alpha_p,
                        float* __restrict__ out)
{
    if (threadIdx.x == 0 && blockIdx.x == 0) {
        const float inv = 1.0f / (float)(Bn * Wn);
        const float pre = accum[0] * inv;
        const float alpha = alpha_p[0];
        const float om = 1.0f - alpha;
        const int base = Bn * Ln * Dn;
        out[base + 0] = pre;              // first_pre_energy
        out[base + 1] = om * om * pre;    // final_post_energy
        out[base + 2] = accum[1] * inv;   // total_update_norm / DIFF_STEPS
        out[base + 3] = accum[2] * inv;   // total_cos_sim / DIFF_STEPS
    }
}

extern "C" void kernel_launch(void* const* d_in, const int* in_sizes, int n_in,
                              void* d_out, int out_size, void* d_ws, size_t ws_size,
                              hipStream_t stream)
{
    const float* x       = (const float*)d_in[0];
    const float* alpha_p = (const float*)d_in[1];
    const float* pos_emb = (const float*)d_in[2];
    const float* w1      = (const float*)d_in[3];
    const float* b1      = (const float*)d_in[4];
    const float* w2      = (const float*)d_in[5];
    const float* b2      = (const float*)d_in[6];
    float* out = (float*)d_out;

    // workspace layout (floats): xw1 [B*L*H] | pew1 [63*H] | accum [4]
    float* xw1  = (float*)d_ws;
    float* pew1 = xw1 + Bn * Ln * Hn;
    float* accum = pew1 + KM1 * Hn;

    hipMemsetAsync(accum, 0, 4 * sizeof(float), stream);

    const int nblkA = (Bn * Ln) / WB + (KM1 + WB - 1) / WB;  // 256 + 8
    k_gemm1<<<nblkA, 128, 0, stream>>>(x, pos_emb, w1, b1, xw1, pew1, out);
    k_main<<<Bn * WCHUNKS, 256, 0, stream>>>(x, alpha_p, w2, b2, xw1, pew1, out, accum);
    k_final<<<1, 64, 0, stream>>>(accum, alpha_p, out);
}

// Round 2
// 139.721 us; speedup vs baseline: 1.7478x; 1.7478x over previous
//
#include <hip/hip_runtime.h>

// Problem constants (match reference)
constexpr int Bn = 2;
constexpr int Ln = 1024;
constexpr int Dn = 768;
constexpr int Hn = 128;          // MLP_HIDDEN
constexpr int KM1 = 63;          // K-1 context positions
constexpr int Wn = 961;          // L-K+1 windows
constexpr int RB = 8;            // rows per block (kernel A)
constexpr int WB = 8;            // windows per block (kernel B2)
constexpr int WCHUNKS = (Wn + WB - 1) / WB;  // 121
constexpr int NROW = Bn * Wn;    // 1922
constexpr float EPSf = 1e-8f;

// ---------------------------------------------------------------------------
// Kernel A: xw1[b,t,h] = x[b,t,:] @ w1[0:D, h]           (2048 rows)
//           pew1[k,h]  = pos_emb[k,:] @ w1[D:2D, h] + b1  (63 rows)
//           + copies unmodified head rows (t < 63) of x into out.
// 1024 threads = (h:128) x (ks:8 K-split of 96). 8 rows staged in LDS.
// 264 blocks x 16 waves = 4224 waves (~4/SIMD).
// ---------------------------------------------------------------------------
__global__ __launch_bounds__(1024)
void k_gemm1(const float* __restrict__ x, const float* __restrict__ pos_emb,
             const float* __restrict__ w1, const float* __restrict__ b1,
             float* __restrict__ xw1, float* __restrict__ pew1,
             float* __restrict__ out)
{
    __shared__ float xs[RB * Dn];        // 24 KiB
    __shared__ float part[8 * RB * Hn];  // 32 KiB
    const int tid = threadIdx.x;
    const int h  = tid & (Hn - 1);
    const int ks = tid >> 7;             // 0..7
    const int blk = blockIdx.x;
    constexpr int KS = Dn / 8;           // 96

    if (blk < (Bn * Ln) / RB) {          // ---- x rows ----
        const int r0 = blk * RB;
        for (int idx = tid; idx < RB * Dn; idx += 1024)
            xs[idx] = x[r0 * Dn + idx];
        __syncthreads();

        // copy unmodified head rows (t < K-1) straight to output
        if (((r0 & (Ln - 1)) < KM1) && tid < Dn) {
            #pragma unroll
            for (int i = 0; i < RB; ++i) {
                const int r = r0 + i;
                if ((r & (Ln - 1)) < KM1)
                    out[r * Dn + tid] = xs[i * Dn + tid];
            }
        }

        float acc[RB];
        #pragma unroll
        for (int i = 0; i < RB; ++i) acc[i] = 0.f;
        const int c0 = ks * KS;
        for (int c = c0; c < c0 + KS; ++c) {
            const float wv = w1[c * Hn + h];          // coalesced, L2
            #pragma unroll
            for (int i = 0; i < RB; ++i)
                acc[i] = fmaf(xs[i * Dn + c], wv, acc[i]);  // LDS broadcast
        }
        #pragma unroll
        for (int i = 0; i < RB; ++i)
            part[(ks * RB + i) * Hn + h] = acc[i];
        __syncthreads();

        // reduce K-splits: thread -> (i = ks, h)
        {
            const int i = ks;
            float s = 0.f;
            #pragma unroll
            for (int k2 = 0; k2 < 8; ++k2)
                s += part[(k2 * RB + i) * Hn + h];
            xw1[(r0 + i) * Hn + h] = s;
        }
    } else {                              // ---- pos_emb rows ----
        const int k0 = (blk - (Bn * Ln) / RB) * RB;
        const int nv = min(RB, KM1 - k0);
        for (int idx = tid; idx < nv * Dn; idx += 1024)
            xs[idx] = pos_emb[k0 * Dn + idx];
        __syncthreads();

        float acc[RB];
        #pragma unroll
        for (int i = 0; i < RB; ++i) acc[i] = 0.f;
        const int c0 = ks * KS;
        for (int c = c0; c < c0 + KS; ++c) {
            const float wv = w1[(Dn + c) * Hn + h];
            #pragma unroll
            for (int i = 0; i < RB; ++i)
                acc[i] = fmaf(xs[i * Dn + c], wv, acc[i]);
        }
        #pragma unroll
        for (int i = 0; i < RB; ++i)
            part[(ks * RB + i) * Hn + h] = acc[i];
        __syncthreads();

        {
            const int i = ks;
            if (i < nv) {
                float s = b1[h];
                #pragma unroll
                for (int k2 = 0; k2 < 8; ++k2)
                    s += part[(k2 * RB + i) * Hn + h];
                pew1[(k0 + i) * Hn + h] = s;
            }
        }
    }
}

// ---------------------------------------------------------------------------
// Kernel B1: hbar[b,w,h] = mean_k relu(xw1[b,w+k,h] + pew1[k,h])
// One block per (b,w): 1922 blocks x 128 threads = 3844 waves. Reads L2.
// ---------------------------------------------------------------------------
__global__ __launch_bounds__(128)
void k_hbar(const float* __restrict__ xw1, const float* __restrict__ pew1,
            float* __restrict__ hbar)
{
    const int h = threadIdx.x;
    const int b = blockIdx.x / Wn;
    const int w = blockIdx.x % Wn;
    const float* xp = xw1 + (b * Ln + w) * Hn + h;
    const float* pp = pew1 + h;
    float s0 = 0.f, s1 = 0.f, s2 = 0.f;
    #pragma unroll
    for (int k = 0; k < KM1; k += 3) {
        s0 += fmaxf(xp[(k    ) * Hn] + pp[(k    ) * Hn], 0.f);
        s1 += fmaxf(xp[(k + 1) * Hn] + pp[(k + 1) * Hn], 0.f);
        s2 += fmaxf(xp[(k + 2) * Hn] + pp[(k + 2) * Hn], 0.f);
    }
    hbar[blockIdx.x * Hn + h] = (s0 + s1 + s2) * (1.0f / 63.0f);
}

// ---------------------------------------------------------------------------
// Kernel B2: per (b, 8-window chunk, d-chunk of 256):
//   pred = hbar @ w2 + b2 ; update/out ; row partials -> atomics on rowacc.
// 726 blocks x 256 threads = 2904 waves. 8 independent accumulators (ILP).
// ---------------------------------------------------------------------------
__global__ __launch_bounds__(256)
void k_gemm2(const float* __restrict__ x, const float* __restrict__ alpha_p,
             const float* __restrict__ w2, const float* __restrict__ b2,
             const float* __restrict__ hbar, float* __restrict__ out,
             float* __restrict__ rowacc)
{
    __shared__ float hs[WB * Hn];     // 4 KiB
    __shared__ float4 red[WB * 256];  // 32 KiB
    const int tid = threadIdx.x;
    int bid = blockIdx.x;
    const int dc = bid % 3; bid /= 3;
    const int chunk = bid % WCHUNKS;
    const int b = bid / WCHUNKS;
    const int w0 = chunk * WB;
    const int wcount = min(WB, Wn - w0);
    const float alpha = alpha_p[0];

    for (int idx = tid; idx < wcount * Hn; idx += 256)
        hs[idx] = hbar[(b * Wn + w0) * Hn + idx];
    __syncthreads();

    const int d = dc * 256 + tid;
    const float bias = b2[d];
    float acc[WB];
    #pragma unroll
    for (int w = 0; w < WB; ++w) acc[w] = bias;
    for (int hh = 0; hh < Hn; ++hh) {
        const float wv = w2[hh * Dn + d];          // coalesced, L2
        #pragma unroll
        for (int w = 0; w < WB; ++w)
            acc[w] = fmaf(hs[w * Hn + hh], wv, acc[w]);  // LDS broadcast
    }

    #pragma unroll
    for (int w = 0; w < WB; ++w) {
        if (w < wcount) {
            const int row = b * Ln + w0 + w + KM1;
            const float cur = x[row * Dn + d];
            const float md = cur - acc[w];
            const float nb = fmaf(-alpha, md, cur);
            out[row * Dn + d] = nb;
            red[w * 256 + tid] = make_float4(md * md, cur * cur, cur * nb, nb * nb);
        } else {
            red[w * 256 + tid] = make_float4(0.f, 0.f, 0.f, 0.f);
        }
    }
    __syncthreads();

    // wave wv reduces windows 2*wv and 2*wv+1
    const int wv = tid >> 6, lane = tid & 63;
    #pragma unroll
    for (int s = 0; s < 2; ++s) {
        const int w = wv * 2 + s;
        float4 a = red[w * 256 + lane];
        const float4 c1 = red[w * 256 + lane + 64];
        const float4 c2 = red[w * 256 + lane + 128];
        const float4 c3 = red[w * 256 + lane + 192];
        float sx = a.x + c1.x + c2.x + c3.x;
        float sy = a.y + c1.y + c2.y + c3.y;
        float sz = a.z + c1.z + c2.z + c3.z;
        float sw = a.w + c1.w + c2.w + c3.w;
        #pragma unroll
        for (int off = 32; off > 0; off >>= 1) {
            sx += __shfl_down(sx, off);
            sy += __shfl_down(sy, off);
            sz += __shfl_down(sz, off);
            sw += __shfl_down(sw, off);
        }
        if (lane == 0 && w < wcount) {
            const int rw = b * Wn + w0 + w;
            atomicAdd(&rowacc[rw * 4 + 0], sx);
            atomicAdd(&rowacc[rw * 4 + 1], sy);
            atomicAdd(&rowacc[rw * 4 + 2], sz);
            atomicAdd(&rowacc[rw * 4 + 3], sw);
        }
    }
}

// ---------------------------------------------------------------------------
// Kernel C: 1922 row-accumulators -> 4 scalar outputs.
// ---------------------------------------------------------------------------
__global__ __launch_bounds__(1024)
void k_final(const float* __restrict__ rowacc, const float* __restrict__ alpha_p,
             float* __restrict__ out)
{
    __shared__ float4 sred[16];
    const int tid = threadIdx.x;
    float se = 0.f, sn = 0.f, sc = 0.f;
    for (int r = tid; r < NROW; r += 1024) {
        const float4 v = ((const float4*)rowacc)[r];
        se += v.x;
        sn += sqrtf(v.x);
        const float na = fmaxf(sqrtf(v.y), EPSf);
        const float nb = fmaxf(sqrtf(v.w), EPSf);
        sc += v.z / (na * nb);
    }
    #pragma unroll
    for (int off = 32; off > 0; off >>= 1) {
        se += __shfl_down(se, off);
        sn += __shfl_down(sn, off);
        sc += __shfl_down(sc, off);
    }
    const int wv = tid >> 6, lane = tid & 63;
    if (lane == 0) sred[wv] = make_float4(se, sn, sc, 0.f);
    __syncthreads();
    if (tid == 0) {
        float te = 0.f, tn = 0.f, tc = 0.f;
        #pragma unroll
        for (int i = 0; i < 16; ++i) {
            te += sred[i].x; tn += sred[i].y; tc += sred[i].z;
        }
        const float alpha = alpha_p[0];
        const float inv = 1.0f / (float)NROW;
        const float pre = te * inv;
        const float om = 1.0f - alpha;
        const int base = Bn * Ln * Dn;
        out[base + 0] = pre;                 // first_pre_energy
        out[base + 1] = om * om * pre;       // final_post_energy
        out[base + 2] = alpha * tn * inv;    // mean update norm
        out[base + 3] = tc * inv;            // mean cos sim
    }
}

extern "C" void kernel_launch(void* const* d_in, const int* in_sizes, int n_in,
                              void* d_out, int out_size, void* d_ws, size_t ws_size,
                              hipStream_t stream)
{
    const float* x       = (const float*)d_in[0];
    const float* alpha_p = (const float*)d_in[1];
    const float* pos_emb = (const float*)d_in[2];
    const float* w1      = (const float*)d_in[3];
    const float* b1      = (const float*)d_in[4];
    const float* w2      = (const float*)d_in[5];
    const float* b2      = (const float*)d_in[6];
    float* out = (float*)d_out;

    // ws layout (floats): xw1 [2048*128] | pew1 [63*128] | hbar [1922*128] | rowacc [1922*4]
    float* xw1    = (float*)d_ws;
    float* pew1   = xw1 + Bn * Ln * Hn;
    float* hbar   = pew1 + KM1 * Hn;
    float* rowacc = hbar + NROW * Hn;

    hipMemsetAsync(rowacc, 0, NROW * 4 * sizeof(float), stream);

    const int nblkA = (Bn * Ln) / RB + (KM1 + RB - 1) / RB;  // 256 + 8 = 264
    k_gemm1<<<nblkA, 1024, 0, stream>>>(x, pos_emb, w1, b1, xw1, pew1, out);
    k_hbar<<<NROW, 128, 0, stream>>>(xw1, pew1, hbar);
    k_gemm2<<<Bn * WCHUNKS * 3, 256, 0, stream>>>(x, alpha_p, w2, b2, hbar, out, rowacc);
    k_final<<<1, 1024, 0, stream>>>(rowacc, alpha_p, out);
}

// Round 3
// 112.098 us; speedup vs baseline: 2.1786x; 1.2464x over previous
//
#include <hip/hip_runtime.h>

constexpr int Bn = 2;
constexpr int Ln = 1024;
constexpr int Dn = 768;
constexpr int Hn = 128;          // MLP_HIDDEN
constexpr int KM1 = 63;          // K-1
constexpr int Wn = 961;          // windows
constexpr int RB = 8;            // rows per block (gemm1)
constexpr int WB = 8;            // windows per chunk (gemm2)
constexpr int WCHUNKS = (Wn + WB - 1) / WB;  // 121
constexpr int NROW = Bn * Wn;    // 1922
constexpr float EPSf = 1e-8f;

__device__ __forceinline__ float4 f4l(const float* p) { return *reinterpret_cast<const float4*>(p); }
__device__ __forceinline__ void f4s(float* p, float4 v) { *reinterpret_cast<float4*>(p) = v; }
__device__ __forceinline__ float4 f4fma(float s, float4 w, float4 a) {
    a.x = fmaf(s, w.x, a.x); a.y = fmaf(s, w.y, a.y);
    a.z = fmaf(s, w.z, a.z); a.w = fmaf(s, w.w, a.w);
    return a;
}

// ---------------------------------------------------------------------------
// Kernel A: xw1 = x @ w1[:D]  (2048 rows) ; pew1 = pos_emb @ w1[D:] + b1 (63)
// + head-row copy. 1024 thr = h4(32) x rowpair(4) x ksplit(8).
// Per f4-iter: 4 float4 global (w1) + 2 ds_read_b128 (xs) + 32 FMA.
// ---------------------------------------------------------------------------
__global__ __launch_bounds__(1024)
void k_gemm1(const float* __restrict__ x, const float* __restrict__ pos_emb,
             const float* __restrict__ w1, const float* __restrict__ b1,
             float* __restrict__ xw1, float* __restrict__ pew1,
             float* __restrict__ out)
{
    __shared__ float xs[RB * Dn];          // 24 KB
    __shared__ float part[8 * RB * Hn];    // 32 KB
    const int tid = threadIdx.x;
    const int h4 = tid & 31;               // h = 4*h4
    const int is = (tid >> 5) & 3;         // row-pair id
    const int ks = tid >> 7;               // 0..7, 96 c each
    const int blk = blockIdx.x;
    constexpr int NXB = (Bn * Ln) / RB;    // 256
    const bool isX = blk < NXB;
    const int peb = blk - NXB;

    const float* src = isX ? (x + blk * RB * Dn) : (pos_emb + peb * RB * Dn);
    const int nv = isX ? RB : min(RB, KM1 - peb * RB);

    for (int idx = tid; idx < nv * (Dn / 4); idx += 1024)
        ((float4*)xs)[idx] = ((const float4*)src)[idx];
    __syncthreads();

    if (isX) {  // head rows (t < K-1) pass through unchanged
        const int r0 = blk * RB;
        if ((r0 & (Ln - 1)) < KM1) {
            for (int idx = tid; idx < RB * (Dn / 4); idx += 1024) {
                const int i = idx / (Dn / 4);
                const int r = r0 + i;
                if ((r & (Ln - 1)) < KM1)
                    ((float4*)out)[r * (Dn / 4) + (idx - i * (Dn / 4))] = ((const float4*)xs)[idx];
            }
        }
    }

    const int woff = isX ? 0 : Dn;
    const int i0 = is * 2;
    float4 acc0 = make_float4(0.f, 0.f, 0.f, 0.f);
    float4 acc1 = acc0;
    const int cbase = ks * (Dn / 8);       // 96-wide c-slice
    for (int cc = 0; cc < Dn / 8; cc += 4) {
        const int c = cbase + cc;
        const float* wp = w1 + (woff + c) * Hn + 4 * h4;
        const float4 wv0 = f4l(wp);
        const float4 wv1 = f4l(wp + Hn);
        const float4 wv2 = f4l(wp + 2 * Hn);
        const float4 wv3 = f4l(wp + 3 * Hn);
        const float4 x0 = ((const float4*)xs)[(i0 * Dn + c) >> 2];
        const float4 x1 = ((const float4*)xs)[((i0 + 1) * Dn + c) >> 2];
        acc0 = f4fma(x0.x, wv0, acc0); acc0 = f4fma(x0.y, wv1, acc0);
        acc0 = f4fma(x0.z, wv2, acc0); acc0 = f4fma(x0.w, wv3, acc0);
        acc1 = f4fma(x1.x, wv0, acc1); acc1 = f4fma(x1.y, wv1, acc1);
        acc1 = f4fma(x1.z, wv2, acc1); acc1 = f4fma(x1.w, wv3, acc1);
    }
    ((float4*)part)[((ks * RB + i0) * Hn + 4 * h4) >> 2] = acc0;
    ((float4*)part)[((ks * RB + i0 + 1) * Hn + 4 * h4) >> 2] = acc1;
    __syncthreads();

    const int oi = tid >> 7;               // 0..7
    const int oh = tid & 127;
    float s = 0.f;
    #pragma unroll
    for (int k2 = 0; k2 < 8; ++k2)
        s += part[(k2 * RB + oi) * Hn + oh];
    if (isX) {
        xw1[(blk * RB + oi) * Hn + oh] = s;
    } else if (oi < nv) {
        pew1[(peb * RB + oi) * Hn + oh] = s + b1[oh];
    }
}

// ---------------------------------------------------------------------------
// Kernel B1: hbar[b,w,:] = mean_k relu(xw1[b,w+k,:] + pew1[k,:])
// 1922 blocks x 256 thr = h4(32) x kgroup(8). float4 everything.
// ---------------------------------------------------------------------------
__global__ __launch_bounds__(256)
void k_hbar(const float* __restrict__ xw1, const float* __restrict__ pew1,
            float* __restrict__ hbar)
{
    __shared__ float4 prt[8][32];
    const int tid = threadIdx.x;
    const int h4 = tid & 31;
    const int kg = tid >> 5;
    const int b = blockIdx.x / Wn;
    const int w = blockIdx.x - b * Wn;
    const float* xp = xw1 + (b * Ln + w + kg * 8) * Hn + 4 * h4;
    const float* pp = pew1 + (kg * 8) * Hn + 4 * h4;
    const int nk = (kg == 7) ? 7 : 8;
    float4 s = make_float4(0.f, 0.f, 0.f, 0.f);
    for (int j = 0; j < nk; ++j) {
        const float4 xv = f4l(xp + j * Hn);
        const float4 pv = f4l(pp + j * Hn);
        s.x += fmaxf(xv.x + pv.x, 0.f);
        s.y += fmaxf(xv.y + pv.y, 0.f);
        s.z += fmaxf(xv.z + pv.z, 0.f);
        s.w += fmaxf(xv.w + pv.w, 0.f);
    }
    prt[kg][h4] = s;
    __syncthreads();
    if (tid < 32) {
        float4 t = prt[0][tid];
        #pragma unroll
        for (int k = 1; k < 8; ++k) {
            const float4 u = prt[k][tid];
            t.x += u.x; t.y += u.y; t.z += u.z; t.w += u.w;
        }
        const float sc = 1.0f / 63.0f;
        t.x *= sc; t.y *= sc; t.z *= sc; t.w *= sc;
        ((float4*)(hbar + blockIdx.x * Hn))[tid] = t;
    }
}

// ---------------------------------------------------------------------------
// Kernel B2: per (b, 8-window chunk, 256-d chunk): pred = hbar @ w2 + b2,
// update/out, per-row partial float4 -> partial[dc][row] (no atomics).
// 726 blocks x 256 thr = d4(64) x hsplit(4).
// ---------------------------------------------------------------------------
__global__ __launch_bounds__(256)
void k_gemm2(const float* __restrict__ x, const float* __restrict__ alpha_p,
             const float* __restrict__ w2, const float* __restrict__ b2,
             const float* __restrict__ hbar, float* __restrict__ out,
             float* __restrict__ partial)
{
    __shared__ float hsm[WB * Hn];        // 4 KB
    __shared__ float4 red[4 * WB * 64];   // 32 KB
    const int tid = threadIdx.x;
    int bid = blockIdx.x;
    const int dc = bid % 3; bid /= 3;
    const int chunk = bid % WCHUNKS;
    const int b = bid / WCHUNKS;
    const int w0 = chunk * WB;
    const int wcount = min(WB, Wn - w0);
    const float alpha = alpha_p[0];

    {
        const float4 z = make_float4(0.f, 0.f, 0.f, 0.f);
        ((float4*)hsm)[tid] = (tid < wcount * (Hn / 4))
            ? ((const float4*)(hbar + (b * Wn + w0) * Hn))[tid] : z;
    }
    __syncthreads();

    const int d4 = tid & 63;
    const int hs = tid >> 6;
    const int d = dc * 256 + d4 * 4;

    float4 acc[WB];
    #pragma unroll
    for (int w = 0; w < WB; ++w) acc[w] = make_float4(0.f, 0.f, 0.f, 0.f);
    const int h0 = hs * 32;
    for (int hh = 0; hh < 32; ++hh) {
        const int h = h0 + hh;
        const float4 wv = f4l(w2 + h * Dn + d);
        #pragma unroll
        for (int w = 0; w < WB; ++w)
            acc[w] = f4fma(hsm[w * Hn + h], wv, acc[w]);
    }
    #pragma unroll
    for (int w = 0; w < WB; ++w)
        red[(hs * WB + w) * 64 + d4] = acc[w];
    __syncthreads();

    // pairs p = 2*tid, 2*tid+1 -> (wloc = p>>6 same for both, dp = p&63)
    const int wloc = tid >> 5;
    float4 pp = make_float4(0.f, 0.f, 0.f, 0.f);
    if (wloc < wcount) {
        const int rowoff = (b * Ln + w0 + wloc + KM1) * Dn + dc * 256;
        #pragma unroll
        for (int j = 0; j < 2; ++j) {
            const int dp = (2 * tid + j) & 63;
            float4 sum = red[wloc * 64 + dp];
            #pragma unroll
            for (int k = 1; k < 4; ++k) {
                const float4 u = red[(k * WB + wloc) * 64 + dp];
                sum.x += u.x; sum.y += u.y; sum.z += u.z; sum.w += u.w;
            }
            const float4 bb = f4l(b2 + dc * 256 + dp * 4);
            const float4 xv = f4l(x + rowoff + dp * 4);
            float4 md;
            md.x = xv.x - (sum.x + bb.x);
            md.y = xv.y - (sum.y + bb.y);
            md.z = xv.z - (sum.z + bb.z);
            md.w = xv.w - (sum.w + bb.w);
            float4 nb;
            nb.x = fmaf(-alpha, md.x, xv.x);
            nb.y = fmaf(-alpha, md.y, xv.y);
            nb.z = fmaf(-alpha, md.z, xv.z);
            nb.w = fmaf(-alpha, md.w, xv.w);
            f4s(out + rowoff + dp * 4, nb);
            pp.x += md.x * md.x + md.y * md.y + md.z * md.z + md.w * md.w;
            pp.y += xv.x * xv.x + xv.y * xv.y + xv.z * xv.z + xv.w * xv.w;
            pp.z += xv.x * nb.x + xv.y * nb.y + xv.z * nb.z + xv.w * nb.w;
            pp.w += nb.x * nb.x + nb.y * nb.y + nb.z * nb.z + nb.w * nb.w;
        }
    }
    #pragma unroll
    for (int off = 16; off > 0; off >>= 1) {
        pp.x += __shfl_xor(pp.x, off);
        pp.y += __shfl_xor(pp.y, off);
        pp.z += __shfl_xor(pp.z, off);
        pp.w += __shfl_xor(pp.w, off);
    }
    if (((tid & 31) == 0) && wloc < wcount)
        f4s(partial + (dc * NROW + b * Wn + w0 + wloc) * 4, pp);
}

// ---------------------------------------------------------------------------
// Kernel C: sum 3 d-chunk partials per row -> 4 scalars.
// ---------------------------------------------------------------------------
__global__ __launch_bounds__(1024)
void k_final(const float* __restrict__ partial, const float* __restrict__ alpha_p,
             float* __restrict__ out)
{
    __shared__ float sred[16][3];
    const int tid = threadIdx.x;
    float se = 0.f, sn = 0.f, sc = 0.f;
    for (int r = tid; r < NROW; r += 1024) {
        const float4 v0 = ((const float4*)partial)[r];
        const float4 v1 = ((const float4*)partial)[NROW + r];
        const float4 v2 = ((const float4*)partial)[2 * NROW + r];
        const float sq = v0.x + v1.x + v2.x;
        const float aa = v0.y + v1.y + v2.y;
        const float ab = v0.z + v1.z + v2.z;
        const float bb = v0.w + v1.w + v2.w;
        se += sq;
        sn += sqrtf(sq);
        sc += ab / (fmaxf(sqrtf(aa), EPSf) * fmaxf(sqrtf(bb), EPSf));
    }
    #pragma unroll
    for (int off = 32; off > 0; off >>= 1) {
        se += __shfl_down(se, off);
        sn += __shfl_down(sn, off);
        sc += __shfl_down(sc, off);
    }
    const int wv = tid >> 6, lane = tid & 63;
    if (lane == 0) { sred[wv][0] = se; sred[wv][1] = sn; sred[wv][2] = sc; }
    __syncthreads();
    if (tid == 0) {
        float te = 0.f, tn = 0.f, tc = 0.f;
        #pragma unroll
        for (int i = 0; i < 16; ++i) {
            te += sred[i][0]; tn += sred[i][1]; tc += sred[i][2];
        }
        const float alpha = alpha_p[0];
        const float inv = 1.0f / (float)NROW;
        const float pre = te * inv;
        const float om = 1.0f - alpha;
        const int base = Bn * Ln * Dn;
        out[base + 0] = pre;
        out[base + 1] = om * om * pre;
        out[base + 2] = alpha * tn * inv;
        out[base + 3] = tc * inv;
    }
}

extern "C" void kernel_launch(void* const* d_in, const int* in_sizes, int n_in,
                              void* d_out, int out_size, void* d_ws, size_t ws_size,
                              hipStream_t stream)
{
    const float* x       = (const float*)d_in[0];
    const float* alpha_p = (const float*)d_in[1];
    const float* pos_emb = (const float*)d_in[2];
    const float* w1      = (const float*)d_in[3];
    const float* b1      = (const float*)d_in[4];
    const float* w2      = (const float*)d_in[5];
    const float* b2      = (const float*)d_in[6];
    float* out = (float*)d_out;

    // ws (floats): xw1 [2048*128] | pew1 [63*128] | hbar [1922*128] | partial [3*1922*4]
    float* xw1     = (float*)d_ws;
    float* pew1    = xw1 + Bn * Ln * Hn;
    float* hbar    = pew1 + KM1 * Hn;
    float* partial = hbar + NROW * Hn;

    const int nblkA = (Bn * Ln) / RB + (KM1 + RB - 1) / RB;  // 264
    k_gemm1<<<nblkA, 1024, 0, stream>>>(x, pos_emb, w1, b1, xw1, pew1, out);
    k_hbar<<<NROW, 256, 0, stream>>>(xw1, pew1, hbar);
    k_gemm2<<<Bn * WCHUNKS * 3, 256, 0, stream>>>(x, alpha_p, w2, b2, hbar, out, partial);
    k_final<<<1, 1024, 0, stream>>>(partial, alpha_p, out);
}

// Round 4
// 107.882 us; speedup vs baseline: 2.2637x; 1.0391x over previous
//
#include <hip/hip_runtime.h>

constexpr int Bn = 2;
constexpr int Ln = 1024;
constexpr int Dn = 768;
constexpr int Hn = 128;          // MLP_HIDDEN
constexpr int KM1 = 63;          // K-1
constexpr int Wn = 961;          // windows
constexpr int RB = 4;            // rows per block (gemm1)
constexpr int WB = 8;            // windows per chunk (fused)
constexpr int WCHUNKS = (Wn + WB - 1) / WB;  // 121
constexpr int NROW = Bn * Wn;    // 1922
constexpr float EPSf = 1e-8f;

__device__ __forceinline__ float4 f4l(const float* p) { return *reinterpret_cast<const float4*>(p); }
__device__ __forceinline__ void f4s(float* p, float4 v) { *reinterpret_cast<float4*>(p) = v; }
__device__ __forceinline__ float4 f4fma(float s, float4 w, float4 a) {
    a.x = fmaf(s, w.x, a.x); a.y = fmaf(s, w.y, a.y);
    a.z = fmaf(s, w.z, a.z); a.w = fmaf(s, w.w, a.w);
    return a;
}

// ---------------------------------------------------------------------------
// Kernel A: xw1 = x @ w1[:D] (2048 rows, 512 blocks) ;
//           pew1 = pos_emb @ w1[D:] + b1 (63 rows, 16 blocks) ; head-row copy.
// 512 thr = h4(32) x ks(16, 48-col slices). Each thread does ALL 4 rows ->
// w1 read exactly ONCE per block (393 KB). 528 blocks ~ 2/CU, 4 waves/SIMD.
// ---------------------------------------------------------------------------
__global__ __launch_bounds__(512)
void k_gemm1(const float* __restrict__ x, const float* __restrict__ pos_emb,
             const float* __restrict__ w1, const float* __restrict__ b1,
             float* __restrict__ xw1, float* __restrict__ pew1,
             float* __restrict__ out)
{
    __shared__ float xs[RB * Dn];            // 12 KB
    __shared__ float part[16 * RB * Hn];     // 32 KB
    const int tid = threadIdx.x;
    const int h4 = tid & 31;                 // h = 4*h4
    const int ks = tid >> 5;                 // 0..15, 48 cols each
    const int blk = blockIdx.x;
    constexpr int NXB = (Bn * Ln) / RB;      // 512
    const bool isX = blk < NXB;
    const int peb = blk - NXB;

    const float* src = isX ? (x + blk * RB * Dn) : (pos_emb + peb * RB * Dn);
    const int nv = isX ? RB : min(RB, KM1 - peb * RB);

    for (int idx = tid; idx < nv * (Dn / 4); idx += 512)
        ((float4*)xs)[idx] = ((const float4*)src)[idx];
    __syncthreads();

    // head rows (t < K-1) pass through unchanged
    if (isX) {
        const int r0 = blk * RB;
        if ((r0 & (Ln - 1)) < KM1) {
            for (int idx = tid; idx < RB * (Dn / 4); idx += 512) {
                const int i = idx / (Dn / 4);
                const int r = r0 + i;
                if ((r & (Ln - 1)) < KM1)
                    ((float4*)out)[r * (Dn / 4) + (idx - i * (Dn / 4))] = ((const float4*)xs)[idx];
            }
        }
    }

    const int woff = isX ? 0 : Dn;
    float4 acc0 = make_float4(0.f, 0.f, 0.f, 0.f);
    float4 acc1 = acc0, acc2 = acc0, acc3 = acc0;
    const int cbase = ks * 48;
    for (int cc = 0; cc < 48; cc += 4) {
        const int c = cbase + cc;
        const float* wp = w1 + (woff + c) * Hn + 4 * h4;
        const float4 wv0 = f4l(wp);
        const float4 wv1 = f4l(wp + Hn);
        const float4 wv2 = f4l(wp + 2 * Hn);
        const float4 wv3 = f4l(wp + 3 * Hn);
        const float4 x0 = ((const float4*)xs)[(0 * Dn + c) >> 2];
        const float4 x1 = ((const float4*)xs)[(1 * Dn + c) >> 2];
        const float4 x2 = ((const float4*)xs)[(2 * Dn + c) >> 2];
        const float4 x3 = ((const float4*)xs)[(3 * Dn + c) >> 2];
        acc0 = f4fma(x0.x, wv0, acc0); acc0 = f4fma(x0.y, wv1, acc0);
        acc0 = f4fma(x0.z, wv2, acc0); acc0 = f4fma(x0.w, wv3, acc0);
        acc1 = f4fma(x1.x, wv0, acc1); acc1 = f4fma(x1.y, wv1, acc1);
        acc1 = f4fma(x1.z, wv2, acc1); acc1 = f4fma(x1.w, wv3, acc1);
        acc2 = f4fma(x2.x, wv0, acc2); acc2 = f4fma(x2.y, wv1, acc2);
        acc2 = f4fma(x2.z, wv2, acc2); acc2 = f4fma(x2.w, wv3, acc2);
        acc3 = f4fma(x3.x, wv0, acc3); acc3 = f4fma(x3.y, wv1, acc3);
        acc3 = f4fma(x3.z, wv2, acc3); acc3 = f4fma(x3.w, wv3, acc3);
    }
    ((float4*)part)[((ks * RB + 0) * Hn + 4 * h4) >> 2] = acc0;
    ((float4*)part)[((ks * RB + 1) * Hn + 4 * h4) >> 2] = acc1;
    ((float4*)part)[((ks * RB + 2) * Hn + 4 * h4) >> 2] = acc2;
    ((float4*)part)[((ks * RB + 3) * Hn + 4 * h4) >> 2] = acc3;
    __syncthreads();

    // reduce 16 k-slices: thread -> (row i = tid>>7, h = tid&127)
    const int oi = tid >> 7;
    const int oh = tid & 127;
    float s = 0.f;
    #pragma unroll
    for (int k2 = 0; k2 < 16; ++k2)
        s += part[(k2 * RB + oi) * Hn + oh];
    if (isX) {
        xw1[(blk * RB + oi) * Hn + oh] = s;
    } else if (oi < nv) {
        pew1[(peb * RB + oi) * Hn + oh] = s + b1[oh];
    }
}

// ---------------------------------------------------------------------------
// Kernel B (fused): per (b, 8-window chunk, 256-d chunk):
//   stage xw1 slab [<=70][128] -> LDS; hbar[8][128] locally;
//   pred = hbar @ w2 + b2 ; update/out ; row partials -> partial[dc][row].
// 726 blocks x 256 thr, 71 KB LDS -> 2 blocks/CU.
// ---------------------------------------------------------------------------
__global__ __launch_bounds__(256)
void k_fused(const float* __restrict__ x, const float* __restrict__ alpha_p,
             const float* __restrict__ w2, const float* __restrict__ b2,
             const float* __restrict__ xw1, const float* __restrict__ pew1,
             float* __restrict__ out, float* __restrict__ partial)
{
    __shared__ float xsl[(WB + KM1 - 1) * Hn];  // 70*128 = 35 KB
    __shared__ float hsm[WB * Hn];              // 4 KB
    __shared__ float4 red[4 * WB * 64];         // 32 KB
    const int tid = threadIdx.x;
    int bid = blockIdx.x;
    const int dc = bid % 3; bid /= 3;
    const int chunk = bid % WCHUNKS;
    const int b = bid / WCHUNKS;
    const int w0 = chunk * WB;
    const int wcount = min(WB, Wn - w0);
    const int nrows = wcount + KM1 - 1;         // <= 70
    const float alpha = alpha_p[0];

    // stage xw1 slab
    {
        const float4* src = (const float4*)(xw1 + (b * Ln + w0) * Hn);
        for (int idx = tid; idx < nrows * (Hn / 4); idx += 256)
            ((float4*)xsl)[idx] = src[idx];
    }
    __syncthreads();

    // hbar[w][h] = mean_k relu(xsl[w+k][h] + pew1[k][h])
    {
        const int w = tid >> 5;                 // 0..7
        const int h4 = tid & 31;
        float4 s = make_float4(0.f, 0.f, 0.f, 0.f);
        const float* pp = pew1 + 4 * h4;
        #pragma unroll 7
        for (int k = 0; k < KM1; ++k) {
            const float4 xv = ((const float4*)xsl)[((w + k) * Hn + 4 * h4) >> 2];
            const float4 pv = f4l(pp + k * Hn);
            s.x += fmaxf(xv.x + pv.x, 0.f);
            s.y += fmaxf(xv.y + pv.y, 0.f);
            s.z += fmaxf(xv.z + pv.z, 0.f);
            s.w += fmaxf(xv.w + pv.w, 0.f);
        }
        const float sc = 1.0f / 63.0f;
        s.x *= sc; s.y *= sc; s.z *= sc; s.w *= sc;
        ((float4*)hsm)[(w * Hn + 4 * h4) >> 2] = s;
    }
    __syncthreads();

    // GEMM2: d4(64) x hs(4)
    const int d4 = tid & 63;
    const int hs = tid >> 6;
    float4 acc[WB];
    #pragma unroll
    for (int w = 0; w < WB; ++w) acc[w] = make_float4(0.f, 0.f, 0.f, 0.f);
    const int d = dc * 256 + d4 * 4;
    const int h0 = hs * 32;
    for (int hh = 0; hh < 32; ++hh) {
        const int h = h0 + hh;
        const float4 wv = f4l(w2 + h * Dn + d);
        #pragma unroll
        for (int w = 0; w < WB; ++w)
            acc[w] = f4fma(hsm[w * Hn + h], wv, acc[w]);
    }
    #pragma unroll
    for (int w = 0; w < WB; ++w)
        red[(hs * WB + w) * 64 + d4] = acc[w];
    __syncthreads();

    // combine h-splits, update/out, row partials
    const int wloc = tid >> 5;
    float4 pp = make_float4(0.f, 0.f, 0.f, 0.f);
    if (wloc < wcount) {
        const int rowoff = (b * Ln + w0 + wloc + KM1) * Dn + dc * 256;
        #pragma unroll
        for (int j = 0; j < 2; ++j) {
            const int dp = (2 * tid + j) & 63;
            float4 sum = red[wloc * 64 + dp];
            #pragma unroll
            for (int k = 1; k < 4; ++k) {
                const float4 u = red[(k * WB + wloc) * 64 + dp];
                sum.x += u.x; sum.y += u.y; sum.z += u.z; sum.w += u.w;
            }
            const float4 bb = f4l(b2 + dc * 256 + dp * 4);
            const float4 xv = f4l(x + rowoff + dp * 4);
            float4 md;
            md.x = xv.x - (sum.x + bb.x);
            md.y = xv.y - (sum.y + bb.y);
            md.z = xv.z - (sum.z + bb.z);
            md.w = xv.w - (sum.w + bb.w);
            float4 nb;
            nb.x = fmaf(-alpha, md.x, xv.x);
            nb.y = fmaf(-alpha, md.y, xv.y);
            nb.z = fmaf(-alpha, md.z, xv.z);
            nb.w = fmaf(-alpha, md.w, xv.w);
            f4s(out + rowoff + dp * 4, nb);
            pp.x += md.x * md.x + md.y * md.y + md.z * md.z + md.w * md.w;
            pp.y += xv.x * xv.x + xv.y * xv.y + xv.z * xv.z + xv.w * xv.w;
            pp.z += xv.x * nb.x + xv.y * nb.y + xv.z * nb.z + xv.w * nb.w;
            pp.w += nb.x * nb.x + nb.y * nb.y + nb.z * nb.z + nb.w * nb.w;
        }
    }
    #pragma unroll
    for (int off = 16; off > 0; off >>= 1) {
        pp.x += __shfl_xor(pp.x, off);
        pp.y += __shfl_xor(pp.y, off);
        pp.z += __shfl_xor(pp.z, off);
        pp.w += __shfl_xor(pp.w, off);
    }
    if (((tid & 31) == 0) && wloc < wcount)
        f4s(partial + (dc * NROW + b * Wn + w0 + wloc) * 4, pp);
}

// ---------------------------------------------------------------------------
// Kernel C: sum 3 d-chunk partials per row -> 4 scalars.
// ---------------------------------------------------------------------------
__global__ __launch_bounds__(1024)
void k_final(const float* __restrict__ partial, const float* __restrict__ alpha_p,
             float* __restrict__ out)
{
    __shared__ float sred[16][3];
    const int tid = threadIdx.x;
    float se = 0.f, sn = 0.f, sc = 0.f;
    for (int r = tid; r < NROW; r += 1024) {
        const float4 v0 = ((const float4*)partial)[r];
        const float4 v1 = ((const float4*)partial)[NROW + r];
        const float4 v2 = ((const float4*)partial)[2 * NROW + r];
        const float sq = v0.x + v1.x + v2.x;
        const float aa = v0.y + v1.y + v2.y;
        const float ab = v0.z + v1.z + v2.z;
        const float bb = v0.w + v1.w + v2.w;
        se += sq;
        sn += sqrtf(sq);
        sc += ab / (fmaxf(sqrtf(aa), EPSf) * fmaxf(sqrtf(bb), EPSf));
    }
    #pragma unroll
    for (int off = 32; off > 0; off >>= 1) {
        se += __shfl_down(se, off);
        sn += __shfl_down(sn, off);
        sc += __shfl_down(sc, off);
    }
    const int wv = tid >> 6, lane = tid & 63;
    if (lane == 0) { sred[wv][0] = se; sred[wv][1] = sn; sred[wv][2] = sc; }
    __syncthreads();
    if (tid == 0) {
        float te = 0.f, tn = 0.f, tc = 0.f;
        #pragma unroll
        for (int i = 0; i < 16; ++i) {
            te += sred[i][0]; tn += sred[i][1]; tc += sred[i][2];
        }
        const float alpha = alpha_p[0];
        const float inv = 1.0f / (float)NROW;
        const float pre = te * inv;
        const float om = 1.0f - alpha;
        const int base = Bn * Ln * Dn;
        out[base + 0] = pre;
        out[base + 1] = om * om * pre;
        out[base + 2] = alpha * tn * inv;
        out[base + 3] = tc * inv;
    }
}

extern "C" void kernel_launch(void* const* d_in, const int* in_sizes, int n_in,
                              void* d_out, int out_size, void* d_ws, size_t ws_size,
                              hipStream_t stream)
{
    const float* x       = (const float*)d_in[0];
    const float* alpha_p = (const float*)d_in[1];
    const float* pos_emb = (const float*)d_in[2];
    const float* w1      = (const float*)d_in[3];
    const float* b1      = (const float*)d_in[4];
    const float* w2      = (const float*)d_in[5];
    const float* b2      = (const float*)d_in[6];
    float* out = (float*)d_out;

    // ws (floats): xw1 [2048*128] | pew1 [63*128] | partial [3*1922*4]
    float* xw1     = (float*)d_ws;
    float* pew1    = xw1 + Bn * Ln * Hn;
    float* partial = pew1 + KM1 * Hn;

    const int nblkA = (Bn * Ln) / RB + (KM1 + RB - 1) / RB;  // 512 + 16 = 528
    k_gemm1<<<nblkA, 512, 0, stream>>>(x, pos_emb, w1, b1, xw1, pew1, out);
    k_fused<<<Bn * WCHUNKS * 3, 256, 0, stream>>>(x, alpha_p, w2, b2, xw1, pew1, out, partial);
    k_final<<<1, 1024, 0, stream>>>(partial, alpha_p, out);
}